// Round 6
// baseline (829.286 us; speedup 1.0000x reference)
//
#include <hip/hip_runtime.h>
#include <hip/hip_cooperative_groups.h>

namespace cg = cooperative_groups;

static constexpr int D = 2048;
static constexpr int H = 4096;
static constexpr int KSTEP = 4;
static constexpr int MAX_STEPS = 64;
static constexpr float MOMC = 0.9f;

static constexpr int GRID = 1024;
static constexpr int BLOCK = 256;

struct Params {
  const float* query;
  const float* hg_Wih; const float* hg_Whh; const float* hg_bih; const float* hg_bhh;
  const float* hd_W; const float* hd_b;
  const float* hc_W; const float* hc_b;
  const float* lg_Wih; const float* lg_Whh; const float* lg_bih; const float* lg_bhh;
  const float* lo_W; const float* lo_b;
  const float* halt_W; const float* halt_b;
  const float* reset_W; const float* reset_b;
  const float* li_W; const float* li_b;
  float* ws; float* out;
};

__device__ __forceinline__ float sigmoidf_(float x) { return 1.f / (1.f + expf(-x)); }

__device__ __forceinline__ float wred(float v) {
  #pragma unroll
  for (int off = 1; off < 64; off <<= 1) v += __shfl_xor(v, off, 64);
  return v;
}

// ---- deep-ILP dots (reduction order identical to R2/R4) ----

// single 2048-length row (8 float4 in flight)
__device__ __forceinline__ float dot8(const float* __restrict__ row,
                                      const float* __restrict__ vec, int lane) {
  float4 a[8];
  #pragma unroll
  for (int g = 0; g < 8; ++g)
    a[g] = *reinterpret_cast<const float4*>(row + g * 256 + lane * 4);
  float s0 = 0.f, s1 = 0.f, s2 = 0.f, s3 = 0.f;
  #pragma unroll
  for (int g = 0; g < 8; g += 4) {
    float4 b0 = *reinterpret_cast<const float4*>(vec + (g + 0) * 256 + lane * 4);
    float4 b1 = *reinterpret_cast<const float4*>(vec + (g + 1) * 256 + lane * 4);
    float4 b2 = *reinterpret_cast<const float4*>(vec + (g + 2) * 256 + lane * 4);
    float4 b3 = *reinterpret_cast<const float4*>(vec + (g + 3) * 256 + lane * 4);
    s0 = fmaf(a[g+0].x, b0.x, s0); s0 = fmaf(a[g+0].y, b0.y, s0);
    s0 = fmaf(a[g+0].z, b0.z, s0); s0 = fmaf(a[g+0].w, b0.w, s0);
    s1 = fmaf(a[g+1].x, b1.x, s1); s1 = fmaf(a[g+1].y, b1.y, s1);
    s1 = fmaf(a[g+1].z, b1.z, s1); s1 = fmaf(a[g+1].w, b1.w, s1);
    s2 = fmaf(a[g+2].x, b2.x, s2); s2 = fmaf(a[g+2].y, b2.y, s2);
    s2 = fmaf(a[g+2].z, b2.z, s2); s2 = fmaf(a[g+2].w, b2.w, s2);
    s3 = fmaf(a[g+3].x, b3.x, s3); s3 = fmaf(a[g+3].y, b3.y, s3);
    s3 = fmaf(a[g+3].z, b3.z, s3); s3 = fmaf(a[g+3].w, b3.w, s3);
  }
  return (s0 + s1) + (s2 + s3);
}

// two independent 2048-length rows (16 float4 in flight)
__device__ __forceinline__ void dot8x2(const float* __restrict__ r0,
                                       const float* __restrict__ r1,
                                       const float* __restrict__ vec,
                                       int lane, float& o0, float& o1) {
  float4 a[8], c[8];
  #pragma unroll
  for (int g = 0; g < 8; ++g)
    a[g] = *reinterpret_cast<const float4*>(r0 + g * 256 + lane * 4);
  #pragma unroll
  for (int g = 0; g < 8; ++g)
    c[g] = *reinterpret_cast<const float4*>(r1 + g * 256 + lane * 4);
  float s0 = 0.f, s1 = 0.f, s2 = 0.f, s3 = 0.f;
  float t0 = 0.f, t1 = 0.f, t2 = 0.f, t3 = 0.f;
  #pragma unroll
  for (int g = 0; g < 8; g += 4) {
    float4 b0 = *reinterpret_cast<const float4*>(vec + (g + 0) * 256 + lane * 4);
    float4 b1 = *reinterpret_cast<const float4*>(vec + (g + 1) * 256 + lane * 4);
    float4 b2 = *reinterpret_cast<const float4*>(vec + (g + 2) * 256 + lane * 4);
    float4 b3 = *reinterpret_cast<const float4*>(vec + (g + 3) * 256 + lane * 4);
    s0 = fmaf(a[g+0].x, b0.x, s0); s0 = fmaf(a[g+0].y, b0.y, s0);
    s0 = fmaf(a[g+0].z, b0.z, s0); s0 = fmaf(a[g+0].w, b0.w, s0);
    s1 = fmaf(a[g+1].x, b1.x, s1); s1 = fmaf(a[g+1].y, b1.y, s1);
    s1 = fmaf(a[g+1].z, b1.z, s1); s1 = fmaf(a[g+1].w, b1.w, s1);
    s2 = fmaf(a[g+2].x, b2.x, s2); s2 = fmaf(a[g+2].y, b2.y, s2);
    s2 = fmaf(a[g+2].z, b2.z, s2); s2 = fmaf(a[g+2].w, b2.w, s2);
    s3 = fmaf(a[g+3].x, b3.x, s3); s3 = fmaf(a[g+3].y, b3.y, s3);
    s3 = fmaf(a[g+3].z, b3.z, s3); s3 = fmaf(a[g+3].w, b3.w, s3);
    t0 = fmaf(c[g+0].x, b0.x, t0); t0 = fmaf(c[g+0].y, b0.y, t0);
    t0 = fmaf(c[g+0].z, b0.z, t0); t0 = fmaf(c[g+0].w, b0.w, t0);
    t1 = fmaf(c[g+1].x, b1.x, t1); t1 = fmaf(c[g+1].y, b1.y, t1);
    t1 = fmaf(c[g+1].z, b1.z, t1); t1 = fmaf(c[g+1].w, b1.w, t1);
    t2 = fmaf(c[g+2].x, b2.x, t2); t2 = fmaf(c[g+2].y, b2.y, t2);
    t2 = fmaf(c[g+2].z, b2.z, t2); t2 = fmaf(c[g+2].w, b2.w, t2);
    t3 = fmaf(c[g+3].x, b3.x, t3); t3 = fmaf(c[g+3].y, b3.y, t3);
    t3 = fmaf(c[g+3].z, b3.z, t3); t3 = fmaf(c[g+3].w, b3.w, t3);
  }
  o0 = (s0 + s1) + (s2 + s3);
  o1 = (t0 + t1) + (t2 + t3);
}

// single 4096-length row (16 float4 in flight)
__device__ __forceinline__ float dot16(const float* __restrict__ row,
                                       const float* __restrict__ vec, int lane) {
  float4 a[16];
  #pragma unroll
  for (int g = 0; g < 16; ++g)
    a[g] = *reinterpret_cast<const float4*>(row + g * 256 + lane * 4);
  float s0 = 0.f, s1 = 0.f, s2 = 0.f, s3 = 0.f;
  #pragma unroll
  for (int g = 0; g < 16; g += 4) {
    float4 b0 = *reinterpret_cast<const float4*>(vec + (g + 0) * 256 + lane * 4);
    float4 b1 = *reinterpret_cast<const float4*>(vec + (g + 1) * 256 + lane * 4);
    float4 b2 = *reinterpret_cast<const float4*>(vec + (g + 2) * 256 + lane * 4);
    float4 b3 = *reinterpret_cast<const float4*>(vec + (g + 3) * 256 + lane * 4);
    s0 = fmaf(a[g+0].x, b0.x, s0); s0 = fmaf(a[g+0].y, b0.y, s0);
    s0 = fmaf(a[g+0].z, b0.z, s0); s0 = fmaf(a[g+0].w, b0.w, s0);
    s1 = fmaf(a[g+1].x, b1.x, s1); s1 = fmaf(a[g+1].y, b1.y, s1);
    s1 = fmaf(a[g+1].z, b1.z, s1); s1 = fmaf(a[g+1].w, b1.w, s1);
    s2 = fmaf(a[g+2].x, b2.x, s2); s2 = fmaf(a[g+2].y, b2.y, s2);
    s2 = fmaf(a[g+2].z, b2.z, s2); s2 = fmaf(a[g+2].w, b2.w, s2);
    s3 = fmaf(a[g+3].x, b3.x, s3); s3 = fmaf(a[g+3].y, b3.y, s3);
    s3 = fmaf(a[g+3].z, b3.z, s3); s3 = fmaf(a[g+3].w, b3.w, s3);
  }
  return (s0 + s1) + (s2 + s3);
}

__global__ void __launch_bounds__(BLOCK, 4) reasoning_kernel(Params p) {
  cg::grid_group grid = cg::this_grid();
  const int tid = blockIdx.x * blockDim.x + threadIdx.x;
  const int nth = gridDim.x * blockDim.x;
  const int lane = threadIdx.x & 63;
  const int gw = tid >> 6;
  const int nw = nth >> 6;

  __shared__ __align__(16) float sh_h[H];   // 16 KB
  __shared__ __align__(16) float sh_l[D];   // 8 KB   (24 KB total -> 4 blocks/CU)

  // ws layout (floats)
  float* qc    = p.ws;           // 3H  q-part of gi (step-invariant)
  float* gi_l  = qc + 3 * H;     // 3H  l-part of gi (upd steps >= 4)
  float* ghh   = gi_l + 3 * H;   // 3H  hg_Whh @ h + bhh
  float* ghl2  = ghh + 3 * H;    // 2 x 3D parity ping-pong
  float* gil   = ghl2 + 6 * D;   // 3D  lg_Wih @ dirv + bih (cached)
  float* dirv  = gil + 3 * D;    // D
  float* resv2 = dirv + D;       // 2 x D parity ping-pong
  float* lrs   = resv2 + 2 * D;  // D  reset projection
  float* scal  = lrs + D;        // 16: [0]=rawconv [1]=halt_h [2]=reset_h
                                 //     [8+par*2+{0,1}] = halt_l, reset_l

  for (int j = threadIdx.x; j < H; j += blockDim.x) sh_h[j] = 0.f;
  for (int j = threadIdx.x; j < D; j += blockDim.x) sh_l[j] = 0.f;
  __syncthreads();

  float cum = 0.f, rw = 0.f, mom = 0.f, sum_reg = 0.f;

  for (int step = 0; step < MAX_STEPS; ++step) {
    const int par = step & 1;
    const bool upd = (step & 3) == 0;
    float* ghl  = ghl2 + par * 3 * D;
    float* resv = resv2 + par * D;

    // ---------------- A phase ----------------
    if (upd) {
      if (step == 0) {
        for (int t = gw * 2; t < 3 * H; t += nw * 2) {
          float o0, o1;
          dot8x2(p.hg_Wih + (size_t)t * (2 * D),
                 p.hg_Wih + (size_t)(t + 1) * (2 * D), p.query, lane, o0, o1);
          o0 = wred(o0); o1 = wred(o1);
          if (lane == 0) { qc[t] = o0; qc[t + 1] = o1; }
        }
      } else {
        for (int t = gw * 2; t < 3 * H; t += nw * 2) {      // gi l-part
          float o0, o1;
          dot8x2(p.hg_Wih + (size_t)t * (2 * D) + D,
                 p.hg_Wih + (size_t)(t + 1) * (2 * D) + D, sh_l, lane, o0, o1);
          o0 = wred(o0); o1 = wred(o1);
          if (lane == 0) { gi_l[t] = o0; gi_l[t + 1] = o1; }
        }
        for (int t = gw; t < 3 * H; t += nw) {              // Whh @ h
          float s = wred(dot16(p.hg_Whh + (size_t)t * H, sh_h, lane)) + p.hg_bhh[t];
          if (lane == 0) ghh[t] = s;
        }
        for (int t = gw * 2; t < 3 * D; t += nw * 2) {      // lg_Whh @ l
          float o0, o1;
          dot8x2(p.lg_Whh + (size_t)t * D,
                 p.lg_Whh + (size_t)(t + 1) * D, sh_l, lane, o0, o1);
          o0 = wred(o0) + p.lg_bhh[t];
          o1 = wred(o1) + p.lg_bhh[t + 1];
          if (lane == 0) { ghl[t] = o0; ghl[t + 1] = o1; }
        }
      }
    } else {
      for (int t = gw * 2; t < 3 * D; t += nw * 2) {
        float o0, o1;
        dot8x2(p.lg_Whh + (size_t)t * D,
               p.lg_Whh + (size_t)(t + 1) * D, sh_l, lane, o0, o1);
        o0 = wred(o0) + p.lg_bhh[t];
        o1 = wred(o1) + p.lg_bhh[t + 1];
        if (lane == 0) { ghl[t] = o0; ghl[t + 1] = o1; }
      }
    }
    grid.sync();  // S1

    if (upd) {
      // ---- P2: h-combine (block-local, identical across blocks) ----
      if (step == 0) {
        for (int i = threadIdx.x; i < H; i += blockDim.x) {
          float r = sigmoidf_(qc[i] + p.hg_bih[i] + p.hg_bhh[i]);
          float z = sigmoidf_(qc[H + i] + p.hg_bih[H + i] + p.hg_bhh[H + i]);
          float n = tanhf(qc[2 * H + i] + p.hg_bih[2 * H + i] + r * p.hg_bhh[2 * H + i]);
          sh_h[i] = (1.f - z) * n;
        }
      } else {
        for (int i = threadIdx.x; i < H; i += blockDim.x) {
          float r = sigmoidf_(qc[i] + gi_l[i] + p.hg_bih[i] + ghh[i]);
          float z = sigmoidf_(qc[H + i] + gi_l[H + i] + p.hg_bih[H + i] + ghh[H + i]);
          float n = tanhf(qc[2 * H + i] + gi_l[2 * H + i] + p.hg_bih[2 * H + i]
                          + r * ghh[2 * H + i]);
          sh_h[i] = (1.f - z) * n + z * sh_h[i];
        }
      }
      __syncthreads();

      // ---- P3: directive + h-derived scalars ----
      for (int t = gw; t < D + 3; t += nw) {
        if (t < D) {
          float s = wred(dot16(p.hd_W + (size_t)t * H, sh_h, lane)) + p.hd_b[t];
          if (lane == 0) dirv[t] = tanhf(s);
        } else if (t == D) {
          float s = wred(dot16(p.hc_W, sh_h, lane)) + p.hc_b[0];
          if (lane == 0) scal[0] = sigmoidf_(s);
        } else if (t == D + 1) {
          float s = wred(dot16(p.halt_W, sh_h, lane));
          if (lane == 0) scal[1] = s;
        } else {
          float s = wred(dot16(p.reset_W, sh_h, lane));
          if (lane == 0) scal[2] = s;
        }
      }
      grid.sync();  // S2

      // ---- P4: gil = lg_Wih @ dirv + bih (dirv read from global; L1-hot) ----
      for (int t = gw * 2; t < 3 * D; t += nw * 2) {
        float o0, o1;
        dot8x2(p.lg_Wih + (size_t)t * D,
               p.lg_Wih + (size_t)(t + 1) * D, dirv, lane, o0, o1);
        o0 = wred(o0) + p.lg_bih[t];
        o1 = wred(o1) + p.lg_bih[t + 1];
        if (lane == 0) { gil[t] = o0; gil[t + 1] = o1; }
      }
      grid.sync();  // S3
    }

    // ---- P5: l-combine (block-local) ----
    if (step == 0) {
      for (int j = threadIdx.x; j < D; j += blockDim.x) {
        float r = sigmoidf_(gil[j] + p.lg_bhh[j]);
        float z = sigmoidf_(gil[D + j] + p.lg_bhh[D + j]);
        float n = tanhf(gil[2 * D + j] + r * p.lg_bhh[2 * D + j]);
        sh_l[j] = (1.f - z) * n;
      }
    } else {
      for (int j = threadIdx.x; j < D; j += blockDim.x) {
        float r = sigmoidf_(gil[j] + ghl[j]);
        float z = sigmoidf_(gil[D + j] + ghl[D + j]);
        float n = tanhf(gil[2 * D + j] + r * ghl[2 * D + j]);
        sh_l[j] = (1.f - z) * n + z * sh_l[j];
      }
    }
    __syncthreads();

    // ---- P6: res + l-derived scalars ----
    for (int pt = gw; pt < D / 2 + 2; pt += nw) {
      if (pt < D / 2) {
        int t = pt * 2;
        float o0, o1;
        dot8x2(p.lo_W + (size_t)t * D,
               p.lo_W + (size_t)(t + 1) * D, sh_l, lane, o0, o1);
        o0 = wred(o0) + p.lo_b[t];
        o1 = wred(o1) + p.lo_b[t + 1];
        if (lane == 0) { resv[t] = tanhf(o0); resv[t + 1] = tanhf(o1); }
      } else if (pt == D / 2) {
        float s = wred(dot8(p.halt_W + H, sh_l, lane));
        if (lane == 0) scal[8 + par * 2 + 0] = s;
      } else {
        float s = wred(dot8(p.reset_W + H, sh_l, lane));
        if (lane == 0) scal[8 + par * 2 + 1] = s;
      }
    }
    grid.sync();  // S4 (S2 on non-update steps)

    // ---- P7: uniform scalar resolution (eager) ----
    mom = MOMC * mom + (1.f - MOMC) * scal[0];
    float halt = sigmoidf_(scal[1] + scal[8 + par * 2 + 0] + p.halt_b[0]);
    float pp = fminf(halt, 1.f - cum);
    cum += pp; rw += pp;
    if (tid < D) sum_reg += pp * resv[tid];
    if (cum > 0.95f) break;

    float reset_p = sigmoidf_(scal[2] + scal[8 + par * 2 + 1] +
                              p.reset_W[H + D] * mom + p.reset_b[0]);
    if ((reset_p > 0.7f) && (step > KSTEP)) {  // uniform branch, all blocks
      for (int t = gw; t < D; t += nw) {
        float s = wred(dot16(p.li_W + (size_t)t * H, sh_h, lane)) + p.li_b[t];
        if (lane == 0) lrs[t] = tanhf(s);
      }
      grid.sync();
      for (int j = threadIdx.x; j < D; j += blockDim.x) sh_l[j] = lrs[j];
      __syncthreads();
    }
  }

  if (tid < D) p.out[tid] = sum_reg / fmaxf(rw, 1e-8f);
}

extern "C" void kernel_launch(void* const* d_in, const int* in_sizes, int n_in,
                              void* d_out, int out_size, void* d_ws, size_t ws_size,
                              hipStream_t stream) {
  Params prm;
  prm.query   = (const float*)d_in[0];
  prm.hg_Wih  = (const float*)d_in[1];
  prm.hg_Whh  = (const float*)d_in[2];
  prm.hg_bih  = (const float*)d_in[3];
  prm.hg_bhh  = (const float*)d_in[4];
  prm.hd_W    = (const float*)d_in[5];
  prm.hd_b    = (const float*)d_in[6];
  prm.hc_W    = (const float*)d_in[7];
  prm.hc_b    = (const float*)d_in[8];
  prm.lg_Wih  = (const float*)d_in[9];
  prm.lg_Whh  = (const float*)d_in[10];
  prm.lg_bih  = (const float*)d_in[11];
  prm.lg_bhh  = (const float*)d_in[12];
  prm.lo_W    = (const float*)d_in[13];
  prm.lo_b    = (const float*)d_in[14];
  prm.halt_W  = (const float*)d_in[15];
  prm.halt_b  = (const float*)d_in[16];
  prm.reset_W = (const float*)d_in[17];
  prm.reset_b = (const float*)d_in[18];
  prm.li_W    = (const float*)d_in[19];
  prm.li_b    = (const float*)d_in[20];
  prm.ws  = (float*)d_ws;
  prm.out = (float*)d_out;

  void* args[] = { &prm };
  const int grids[4] = { GRID, GRID / 2, GRID / 4, GRID / 8 };
  for (int g = 0; g < 4; ++g) {
    hipError_t e = hipLaunchCooperativeKernel((const void*)reasoning_kernel,
                                              dim3(grids[g]), dim3(BLOCK),
                                              args, 0, stream);
    if (e == hipSuccess) break;
  }
}

// Round 10
// 214.404 us; speedup vs baseline: 3.8679x; 3.8679x over previous
//
#include <hip/hip_runtime.h>
#include <hip/hip_cooperative_groups.h>

namespace cg = cooperative_groups;

static constexpr int D = 2048;
static constexpr int H = 4096;
static constexpr int KSTEP = 4;
static constexpr int MAX_STEPS = 64;
static constexpr float MOMC = 0.9f;

static constexpr int GRID = 256;    // 1 block/CU: far from the co-residency
static constexpr int BLOCK = 512;   // cliff that deadlocked R6/R7/R8 (512 blks)

struct Params {
  const float* query;
  const float* hg_Wih; const float* hg_Whh; const float* hg_bih; const float* hg_bhh;
  const float* hd_W; const float* hd_b;
  const float* hc_W; const float* hc_b;
  const float* lg_Wih; const float* lg_Whh; const float* lg_bih; const float* lg_bhh;
  const float* lo_W; const float* lo_b;
  const float* halt_W; const float* halt_b;
  const float* reset_W; const float* reset_b;
  const float* li_W; const float* li_b;
  float* ws; float* out;
};

__device__ __forceinline__ float sigmoidf_(float x) { return 1.f / (1.f + expf(-x)); }

__device__ __forceinline__ float wred(float v) {
  #pragma unroll
  for (int off = 1; off < 64; off <<= 1) v += __shfl_xor(v, off, 64);
  return v;
}

// ---- deep-ILP dots (identical reduction order + codegen to R4:
//      proven VGPR=128, zero spill at __launch_bounds__(512,2)) ----
__device__ __forceinline__ void dot8x2(const float* __restrict__ r0,
                                       const float* __restrict__ r1,
                                       const float* __restrict__ vec,
                                       int lane, float& o0, float& o1) {
  float4 a[8], c[8];
  #pragma unroll
  for (int g = 0; g < 8; ++g)
    a[g] = *reinterpret_cast<const float4*>(r0 + g * 256 + lane * 4);
  #pragma unroll
  for (int g = 0; g < 8; ++g)
    c[g] = *reinterpret_cast<const float4*>(r1 + g * 256 + lane * 4);
  float s0 = 0.f, s1 = 0.f, s2 = 0.f, s3 = 0.f;
  float t0 = 0.f, t1 = 0.f, t2 = 0.f, t3 = 0.f;
  #pragma unroll
  for (int g = 0; g < 8; g += 4) {
    float4 b0 = *reinterpret_cast<const float4*>(vec + (g + 0) * 256 + lane * 4);
    float4 b1 = *reinterpret_cast<const float4*>(vec + (g + 1) * 256 + lane * 4);
    float4 b2 = *reinterpret_cast<const float4*>(vec + (g + 2) * 256 + lane * 4);
    float4 b3 = *reinterpret_cast<const float4*>(vec + (g + 3) * 256 + lane * 4);
    s0 = fmaf(a[g+0].x, b0.x, s0); s0 = fmaf(a[g+0].y, b0.y, s0);
    s0 = fmaf(a[g+0].z, b0.z, s0); s0 = fmaf(a[g+0].w, b0.w, s0);
    s1 = fmaf(a[g+1].x, b1.x, s1); s1 = fmaf(a[g+1].y, b1.y, s1);
    s1 = fmaf(a[g+1].z, b1.z, s1); s1 = fmaf(a[g+1].w, b1.w, s1);
    s2 = fmaf(a[g+2].x, b2.x, s2); s2 = fmaf(a[g+2].y, b2.y, s2);
    s2 = fmaf(a[g+2].z, b2.z, s2); s2 = fmaf(a[g+2].w, b2.w, s2);
    s3 = fmaf(a[g+3].x, b3.x, s3); s3 = fmaf(a[g+3].y, b3.y, s3);
    s3 = fmaf(a[g+3].z, b3.z, s3); s3 = fmaf(a[g+3].w, b3.w, s3);
    t0 = fmaf(c[g+0].x, b0.x, t0); t0 = fmaf(c[g+0].y, b0.y, t0);
    t0 = fmaf(c[g+0].z, b0.z, t0); t0 = fmaf(c[g+0].w, b0.w, t0);
    t1 = fmaf(c[g+1].x, b1.x, t1); t1 = fmaf(c[g+1].y, b1.y, t1);
    t1 = fmaf(c[g+1].z, b1.z, t1); t1 = fmaf(c[g+1].w, b1.w, t1);
    t2 = fmaf(c[g+2].x, b2.x, t2); t2 = fmaf(c[g+2].y, b2.y, t2);
    t2 = fmaf(c[g+2].z, b2.z, t2); t2 = fmaf(c[g+2].w, b2.w, t2);
    t3 = fmaf(c[g+3].x, b3.x, t3); t3 = fmaf(c[g+3].y, b3.y, t3);
    t3 = fmaf(c[g+3].z, b3.z, t3); t3 = fmaf(c[g+3].w, b3.w, t3);
  }
  o0 = (s0 + s1) + (s2 + s3);
  o1 = (t0 + t1) + (t2 + t3);
}

__device__ __forceinline__ float dot16(const float* __restrict__ row,
                                       const float* __restrict__ vec, int lane) {
  float4 a[16];
  #pragma unroll
  for (int g = 0; g < 16; ++g)
    a[g] = *reinterpret_cast<const float4*>(row + g * 256 + lane * 4);
  float s0 = 0.f, s1 = 0.f, s2 = 0.f, s3 = 0.f;
  #pragma unroll
  for (int g = 0; g < 16; g += 4) {
    float4 b0 = *reinterpret_cast<const float4*>(vec + (g + 0) * 256 + lane * 4);
    float4 b1 = *reinterpret_cast<const float4*>(vec + (g + 1) * 256 + lane * 4);
    float4 b2 = *reinterpret_cast<const float4*>(vec + (g + 2) * 256 + lane * 4);
    float4 b3 = *reinterpret_cast<const float4*>(vec + (g + 3) * 256 + lane * 4);
    s0 = fmaf(a[g+0].x, b0.x, s0); s0 = fmaf(a[g+0].y, b0.y, s0);
    s0 = fmaf(a[g+0].z, b0.z, s0); s0 = fmaf(a[g+0].w, b0.w, s0);
    s1 = fmaf(a[g+1].x, b1.x, s1); s1 = fmaf(a[g+1].y, b1.y, s1);
    s1 = fmaf(a[g+1].z, b1.z, s1); s1 = fmaf(a[g+1].w, b1.w, s1);
    s2 = fmaf(a[g+2].x, b2.x, s2); s2 = fmaf(a[g+2].y, b2.y, s2);
    s2 = fmaf(a[g+2].z, b2.z, s2); s2 = fmaf(a[g+2].w, b2.w, s2);
    s3 = fmaf(a[g+3].x, b3.x, s3); s3 = fmaf(a[g+3].y, b3.y, s3);
    s3 = fmaf(a[g+3].z, b3.z, s3); s3 = fmaf(a[g+3].w, b3.w, s3);
  }
  return (s0 + s1) + (s2 + s3);
}

__global__ void __launch_bounds__(BLOCK, 2) reasoning_kernel(Params p) {
  cg::grid_group grid = cg::this_grid();
  const int tid = blockIdx.x * blockDim.x + threadIdx.x;
  const int nth = gridDim.x * blockDim.x;
  const int lane = threadIdx.x & 63;
  const int wid = threadIdx.x >> 6;   // wave in block, 0..7
  const int gw = tid >> 6;
  const int nw = nth >> 6;

  __shared__ __align__(16) float sh_h[H];    // 16 KB
  __shared__ __align__(16) float sh_l[D];    // 8 KB
  __shared__ __align__(16) float sh_dir[D];  // 8 KB
  __shared__ float sh_red[32];

  // ws layout (floats): 57344 total = 229 KB (within proven envelope)
  float* qc   = p.ws;            // 3H  step-invariant q-part of gi
  float* gi_l = qc + 3 * H;      // 3H
  float* ghh  = gi_l + 3 * H;    // 3H
  float* ghl2 = ghh + 3 * H;     // 2 x 3D parity ping-pong
  float* gil  = ghl2 + 6 * D;    // 3D  (cached between h-updates)
  float* dirv = gil + 3 * D;     // D   (also reused as reset projection)

  for (int j = threadIdx.x; j < H; j += blockDim.x) sh_h[j] = 0.f;
  for (int j = threadIdx.x; j < D; j += blockDim.x) sh_l[j] = 0.f;
  __syncthreads();

  float cum = 0.f, rw = 0.f, mom = 0.f;
  float rawconv = 0.f, halt_h = 0.f, reset_h = 0.f;   // cached across steps
  float sum0 = 0.f, sum1 = 0.f;                       // owner-wave output acc
  const bool owner = (gw < D / 2);                    // wave gw owns rows 2gw, 2gw+1

  for (int step = 0; step < MAX_STEPS; ++step) {
    const int par = step & 1;
    const bool upd = (step & 3) == 0;
    float* ghl = ghl2 + par * 3 * D;

    // ---------------- A phase (grid-distributed dots) ----------------
    if (upd) {
      if (step == 0) {
        for (int t = gw * 2; t < 3 * H; t += nw * 2) {
          float o0, o1;
          dot8x2(p.hg_Wih + (size_t)t * (2 * D),
                 p.hg_Wih + (size_t)(t + 1) * (2 * D), p.query, lane, o0, o1);
          o0 = wred(o0); o1 = wred(o1);
          if (lane == 0) { qc[t] = o0; qc[t + 1] = o1; }
        }
      } else {
        for (int t = gw * 2; t < 3 * H; t += nw * 2) {      // gi l-part
          float o0, o1;
          dot8x2(p.hg_Wih + (size_t)t * (2 * D) + D,
                 p.hg_Wih + (size_t)(t + 1) * (2 * D) + D, sh_l, lane, o0, o1);
          o0 = wred(o0); o1 = wred(o1);
          if (lane == 0) { gi_l[t] = o0; gi_l[t + 1] = o1; }
        }
        for (int t = gw; t < 3 * H; t += nw) {              // Whh @ h
          float s = wred(dot16(p.hg_Whh + (size_t)t * H, sh_h, lane));
          if (lane == 0) ghh[t] = s + p.hg_bhh[t];
        }
        for (int t = gw * 2; t < 3 * D; t += nw * 2) {      // lg_Whh @ l
          float o0, o1;
          dot8x2(p.lg_Whh + (size_t)t * D,
                 p.lg_Whh + (size_t)(t + 1) * D, sh_l, lane, o0, o1);
          o0 = wred(o0); o1 = wred(o1);
          if (lane == 0) { ghl[t] = o0 + p.lg_bhh[t]; ghl[t + 1] = o1 + p.lg_bhh[t + 1]; }
        }
      }
    } else {
      for (int t = gw * 2; t < 3 * D; t += nw * 2) {
        float o0, o1;
        dot8x2(p.lg_Whh + (size_t)t * D,
               p.lg_Whh + (size_t)(t + 1) * D, sh_l, lane, o0, o1);
        o0 = wred(o0); o1 = wred(o1);
        if (lane == 0) { ghl[t] = o0 + p.lg_bhh[t]; ghl[t + 1] = o1 + p.lg_bhh[t + 1]; }
      }
    }
    grid.sync();  // S1

    if (upd) {
      // ---- h-combine, block-local (identical across blocks) ----
      if (step == 0) {
        for (int i = threadIdx.x; i < H; i += blockDim.x) {
          float r = sigmoidf_(qc[i] + p.hg_bih[i] + p.hg_bhh[i]);
          float z = sigmoidf_(qc[H + i] + p.hg_bih[H + i] + p.hg_bhh[H + i]);
          float n = tanhf(qc[2 * H + i] + p.hg_bih[2 * H + i] + r * p.hg_bhh[2 * H + i]);
          sh_h[i] = (1.f - z) * n;
        }
      } else {
        for (int i = threadIdx.x; i < H; i += blockDim.x) {
          float r = sigmoidf_(qc[i] + gi_l[i] + p.hg_bih[i] + ghh[i]);
          float z = sigmoidf_(qc[H + i] + gi_l[H + i] + p.hg_bih[H + i] + ghh[H + i]);
          float n = tanhf(qc[2 * H + i] + gi_l[2 * H + i] + p.hg_bih[2 * H + i]
                          + r * ghh[2 * H + i]);
          sh_h[i] = (1.f - z) * n + z * sh_h[i];
        }
      }
      __syncthreads();

      // ---- block-local h scalars: rawconv / halt_h / reset_h ----
      {
        float a0 = 0.f, a1 = 0.f, a2 = 0.f;
        for (int k = threadIdx.x; k < H; k += BLOCK) {
          float hv = sh_h[k];
          a0 = fmaf(p.hc_W[k], hv, a0);
          a1 = fmaf(p.halt_W[k], hv, a1);
          a2 = fmaf(p.reset_W[k], hv, a2);
        }
        a0 = wred(a0); a1 = wred(a1); a2 = wred(a2);
        if (lane == 0) { sh_red[wid] = a0; sh_red[8 + wid] = a1; sh_red[16 + wid] = a2; }
        __syncthreads();
        float t0 = 0.f, t1 = 0.f, t2 = 0.f;
        #pragma unroll
        for (int w = 0; w < 8; ++w) { t0 += sh_red[w]; t1 += sh_red[8 + w]; t2 += sh_red[16 + w]; }
        rawconv = sigmoidf_(t0 + p.hc_b[0]);
        halt_h = t1; reset_h = t2;
        __syncthreads();
      }

      // ---- dirv dots (grid-distributed) ----
      for (int t = gw; t < D; t += nw) {
        float s = wred(dot16(p.hd_W + (size_t)t * H, sh_h, lane));
        if (lane == 0) dirv[t] = tanhf(s + p.hd_b[t]);
      }
      grid.sync();  // S2

      for (int j = threadIdx.x; j < D; j += blockDim.x) sh_dir[j] = dirv[j];
      __syncthreads();

      // ---- gil = lg_Wih @ dirv + bih ----
      for (int t = gw * 2; t < 3 * D; t += nw * 2) {
        float o0, o1;
        dot8x2(p.lg_Wih + (size_t)t * D,
               p.lg_Wih + (size_t)(t + 1) * D, sh_dir, lane, o0, o1);
        o0 = wred(o0); o1 = wred(o1);
        if (lane == 0) { gil[t] = o0 + p.lg_bih[t]; gil[t + 1] = o1 + p.lg_bih[t + 1]; }
      }
      grid.sync();  // S3
    }

    // ---- l-combine, block-local ----
    if (step == 0) {
      for (int j = threadIdx.x; j < D; j += blockDim.x) {
        float r = sigmoidf_(gil[j] + p.lg_bhh[j]);
        float z = sigmoidf_(gil[D + j] + p.lg_bhh[D + j]);
        float n = tanhf(gil[2 * D + j] + r * p.lg_bhh[2 * D + j]);
        sh_l[j] = (1.f - z) * n;
      }
    } else {
      for (int j = threadIdx.x; j < D; j += blockDim.x) {
        float r = sigmoidf_(gil[j] + ghl[j]);
        float z = sigmoidf_(gil[D + j] + ghl[D + j]);
        float n = tanhf(gil[2 * D + j] + r * ghl[2 * D + j]);
        sh_l[j] = (1.f - z) * n + z * sh_l[j];
      }
    }
    __syncthreads();

    // ---- block-local l scalars: halt_l / reset_l ----
    float halt_l, reset_l;
    {
      float a0 = 0.f, a1 = 0.f;
      for (int k = threadIdx.x; k < D; k += BLOCK) {
        float lv = sh_l[k];
        a0 = fmaf(p.halt_W[H + k], lv, a0);
        a1 = fmaf(p.reset_W[H + k], lv, a1);
      }
      a0 = wred(a0); a1 = wred(a1);
      if (lane == 0) { sh_red[wid] = a0; sh_red[8 + wid] = a1; }
      __syncthreads();
      float t0 = 0.f, t1 = 0.f;
      #pragma unroll
      for (int w = 0; w < 8; ++w) { t0 += sh_red[w]; t1 += sh_red[8 + w]; }
      halt_l = t0; reset_l = t1;
      __syncthreads();
    }

    // ---- scalar resolution (uniform, block-local — no barrier needed) ----
    mom = MOMC * mom + (1.f - MOMC) * rawconv;
    float halt = sigmoidf_(halt_h + halt_l + p.halt_b[0]);
    float pp = fminf(halt, 1.f - cum);
    cum += pp; rw += pp;
    bool converged = cum > 0.95f;

    // ---- res rows: owner waves accumulate into registers (no exchange);
    //      non-owner waves fall through into the next A-phase naturally ----
    if (owner) {
      int t = gw * 2;
      float o0, o1;
      dot8x2(p.lo_W + (size_t)t * D, p.lo_W + (size_t)(t + 1) * D, sh_l, lane, o0, o1);
      o0 = wred(o0); o1 = wred(o1);
      sum0 += pp * tanhf(o0 + p.lo_b[t]);
      sum1 += pp * tanhf(o1 + p.lo_b[t + 1]);
    }
    if (converged) break;

    float reset_p = sigmoidf_(reset_h + reset_l + p.reset_W[H + D] * mom + p.reset_b[0]);
    if ((reset_p > 0.7f) && (step > KSTEP)) {  // uniform across blocks
      for (int t = gw; t < D; t += nw) {
        float s = wred(dot16(p.li_W + (size_t)t * H, sh_h, lane));
        if (lane == 0) dirv[t] = tanhf(s + p.li_b[t]);   // dirv reused as lrs
      }
      grid.sync();
      for (int j = threadIdx.x; j < D; j += blockDim.x) sh_l[j] = dirv[j];
      __syncthreads();
    }
    // no trailing sync: every cross-block RW pair spans >=1 grid.sync (audited)
  }

  if (owner && lane == 0) {
    float inv = 1.f / fmaxf(rw, 1e-8f);
    p.out[2 * gw]     = sum0 * inv;
    p.out[2 * gw + 1] = sum1 * inv;
  }
}

extern "C" void kernel_launch(void* const* d_in, const int* in_sizes, int n_in,
                              void* d_out, int out_size, void* d_ws, size_t ws_size,
                              hipStream_t stream) {
  Params prm;
  prm.query   = (const float*)d_in[0];
  prm.hg_Wih  = (const float*)d_in[1];
  prm.hg_Whh  = (const float*)d_in[2];
  prm.hg_bih  = (const float*)d_in[3];
  prm.hg_bhh  = (const float*)d_in[4];
  prm.hd_W    = (const float*)d_in[5];
  prm.hd_b    = (const float*)d_in[6];
  prm.hc_W    = (const float*)d_in[7];
  prm.hc_b    = (const float*)d_in[8];
  prm.lg_Wih  = (const float*)d_in[9];
  prm.lg_Whh  = (const float*)d_in[10];
  prm.lg_bih  = (const float*)d_in[11];
  prm.lg_bhh  = (const float*)d_in[12];
  prm.lo_W    = (const float*)d_in[13];
  prm.lo_b    = (const float*)d_in[14];
  prm.halt_W  = (const float*)d_in[15];
  prm.halt_b  = (const float*)d_in[16];
  prm.reset_W = (const float*)d_in[17];
  prm.reset_b = (const float*)d_in[18];
  prm.li_W    = (const float*)d_in[19];
  prm.li_b    = (const float*)d_in[20];
  prm.ws  = (float*)d_ws;
  prm.out = (float*)d_out;

  void* args[] = { &prm };
  const int grids[3] = { GRID, GRID / 2, GRID / 4 };
  for (int g = 0; g < 3; ++g) {
    hipError_t e = hipLaunchCooperativeKernel((const void*)reasoning_kernel,
                                              dim3(grids[g]), dim3(BLOCK),
                                              args, 0, stream);
    if (e == hipSuccess) break;
  }
}

// Round 11
// 117.710 us; speedup vs baseline: 7.0452x; 1.8215x over previous
//
#include <hip/hip_runtime.h>

static constexpr int D = 2048;
static constexpr int H = 4096;
static constexpr int KSTEP = 4;
static constexpr int MAX_STEPS = 64;
static constexpr float MOMC = 0.9f;

static constexpr int GRID = 256;    // 1 block/CU — proven launchable 5x.
static constexpr int BLOCK = 512;   // bounds(512,2): VGPR=128, no spill (proven)

// ws float layout: qc 3H | gi_l 3H | ghh 3H | ghl2 2x3D | gil 3D | dirv D
//                = 57344 floats (229376 B); barrier region 4 KB after that.
// Total 233472 B < 254016 B proven addressable in R4/R5.
static constexpr int BAR_OFF_FLOATS = 57344;

struct Params {
  const float* query;
  const float* hg_Wih; const float* hg_Whh; const float* hg_bih; const float* hg_bhh;
  const float* hd_W; const float* hd_b;
  const float* hc_W; const float* hc_b;
  const float* lg_Wih; const float* lg_Whh; const float* lg_bih; const float* lg_bhh;
  const float* lo_W; const float* lo_b;
  const float* halt_W; const float* halt_b;
  const float* reset_W; const float* reset_b;
  const float* li_W; const float* li_b;
  float* ws; float* out;
};

__device__ __forceinline__ float sigmoidf_(float x) { return 1.f / (1.f + expf(-x)); }

// Agent-scope (LLC-coherent) accessors for ALL cross-block ws data.
// These bypass the non-coherent per-XCD L2 — no cache flush ever needed.
__device__ __forceinline__ void cstore(float* p, float v) {
  __hip_atomic_store(p, v, __ATOMIC_RELAXED, __HIP_MEMORY_SCOPE_AGENT);
}
__device__ __forceinline__ float cload(const float* p) {
  return __hip_atomic_load(p, __ATOMIC_RELAXED, __HIP_MEMORY_SCOPE_AGENT);
}

// 16-leaf + root + generation tree barrier. Coherence comes from sc1 data
// accesses, not from fences: weights stay hot in L2 across the whole kernel.
// Deadlock-free at GRID<=256 (all blocks co-resident, uniform control flow).
__device__ __forceinline__ void gridbar(unsigned* bar, unsigned& mygen) {
  __syncthreads();   // drains vmcnt per wave -> all block stores LLC-visible
  if (threadIdx.x == 0) {
    unsigned* leaf = bar + (blockIdx.x & 15) * 32;   // 128B-spaced lines
    unsigned* root = bar + 16 * 32;
    unsigned* gen  = bar + 17 * 32;
    const unsigned leafcnt = gridDim.x >> 4;         // grids are multiples of 16
    const unsigned want = mygen + 1;
    unsigned old = __hip_atomic_fetch_add(leaf, 1u, __ATOMIC_RELEASE, __HIP_MEMORY_SCOPE_AGENT);
    if (old == leafcnt - 1u) {
      __hip_atomic_store(leaf, 0u, __ATOMIC_RELAXED, __HIP_MEMORY_SCOPE_AGENT);
      unsigned ro = __hip_atomic_fetch_add(root, 1u, __ATOMIC_ACQ_REL, __HIP_MEMORY_SCOPE_AGENT);
      if (ro == 15u) {
        __hip_atomic_store(root, 0u, __ATOMIC_RELAXED, __HIP_MEMORY_SCOPE_AGENT);
        __hip_atomic_store(gen, want, __ATOMIC_RELEASE, __HIP_MEMORY_SCOPE_AGENT);
      } else {
        while (__hip_atomic_load(gen, __ATOMIC_RELAXED, __HIP_MEMORY_SCOPE_AGENT) != want)
          __builtin_amdgcn_s_sleep(2);
      }
    } else {
      while (__hip_atomic_load(gen, __ATOMIC_RELAXED, __HIP_MEMORY_SCOPE_AGENT) != want)
        __builtin_amdgcn_s_sleep(2);
    }
  }
  mygen += 1;
  __syncthreads();
}

__device__ __forceinline__ float wred(float v) {
  #pragma unroll
  for (int off = 1; off < 64; off <<= 1) v += __shfl_xor(v, off, 64);
  return v;
}

// ---- deep-ILP dots (reduction order identical to R2/R4/R9) ----
__device__ __forceinline__ float dot8(const float* __restrict__ row,
                                      const float* __restrict__ vec, int lane) {
  float4 a[8];
  #pragma unroll
  for (int g = 0; g < 8; ++g)
    a[g] = *reinterpret_cast<const float4*>(row + g * 256 + lane * 4);
  float s0 = 0.f, s1 = 0.f, s2 = 0.f, s3 = 0.f;
  #pragma unroll
  for (int g = 0; g < 8; g += 4) {
    float4 b0 = *reinterpret_cast<const float4*>(vec + (g + 0) * 256 + lane * 4);
    float4 b1 = *reinterpret_cast<const float4*>(vec + (g + 1) * 256 + lane * 4);
    float4 b2 = *reinterpret_cast<const float4*>(vec + (g + 2) * 256 + lane * 4);
    float4 b3 = *reinterpret_cast<const float4*>(vec + (g + 3) * 256 + lane * 4);
    s0 = fmaf(a[g+0].x, b0.x, s0); s0 = fmaf(a[g+0].y, b0.y, s0);
    s0 = fmaf(a[g+0].z, b0.z, s0); s0 = fmaf(a[g+0].w, b0.w, s0);
    s1 = fmaf(a[g+1].x, b1.x, s1); s1 = fmaf(a[g+1].y, b1.y, s1);
    s1 = fmaf(a[g+1].z, b1.z, s1); s1 = fmaf(a[g+1].w, b1.w, s1);
    s2 = fmaf(a[g+2].x, b2.x, s2); s2 = fmaf(a[g+2].y, b2.y, s2);
    s2 = fmaf(a[g+2].z, b2.z, s2); s2 = fmaf(a[g+2].w, b2.w, s2);
    s3 = fmaf(a[g+3].x, b3.x, s3); s3 = fmaf(a[g+3].y, b3.y, s3);
    s3 = fmaf(a[g+3].w, b3.w, s3); s3 = fmaf(a[g+3].z, b3.z, s3);
  }
  return (s0 + s1) + (s2 + s3);
}

__device__ __forceinline__ void dot8x2(const float* __restrict__ r0,
                                       const float* __restrict__ r1,
                                       const float* __restrict__ vec,
                                       int lane, float& o0, float& o1) {
  float4 a[8], c[8];
  #pragma unroll
  for (int g = 0; g < 8; ++g)
    a[g] = *reinterpret_cast<const float4*>(r0 + g * 256 + lane * 4);
  #pragma unroll
  for (int g = 0; g < 8; ++g)
    c[g] = *reinterpret_cast<const float4*>(r1 + g * 256 + lane * 4);
  float s0 = 0.f, s1 = 0.f, s2 = 0.f, s3 = 0.f;
  float t0 = 0.f, t1 = 0.f, t2 = 0.f, t3 = 0.f;
  #pragma unroll
  for (int g = 0; g < 8; g += 4) {
    float4 b0 = *reinterpret_cast<const float4*>(vec + (g + 0) * 256 + lane * 4);
    float4 b1 = *reinterpret_cast<const float4*>(vec + (g + 1) * 256 + lane * 4);
    float4 b2 = *reinterpret_cast<const float4*>(vec + (g + 2) * 256 + lane * 4);
    float4 b3 = *reinterpret_cast<const float4*>(vec + (g + 3) * 256 + lane * 4);
    s0 = fmaf(a[g+0].x, b0.x, s0); s0 = fmaf(a[g+0].y, b0.y, s0);
    s0 = fmaf(a[g+0].z, b0.z, s0); s0 = fmaf(a[g+0].w, b0.w, s0);
    s1 = fmaf(a[g+1].x, b1.x, s1); s1 = fmaf(a[g+1].y, b1.y, s1);
    s1 = fmaf(a[g+1].z, b1.z, s1); s1 = fmaf(a[g+1].w, b1.w, s1);
    s2 = fmaf(a[g+2].x, b2.x, s2); s2 = fmaf(a[g+2].y, b2.y, s2);
    s2 = fmaf(a[g+2].z, b2.z, s2); s2 = fmaf(a[g+2].w, b2.w, s2);
    s3 = fmaf(a[g+3].x, b3.x, s3); s3 = fmaf(a[g+3].y, b3.y, s3);
    s3 = fmaf(a[g+3].z, b3.z, s3); s3 = fmaf(a[g+3].w, b3.w, s3);
    t0 = fmaf(c[g+0].x, b0.x, t0); t0 = fmaf(c[g+0].y, b0.y, t0);
    t0 = fmaf(c[g+0].z, b0.z, t0); t0 = fmaf(c[g+0].w, b0.w, t0);
    t1 = fmaf(c[g+1].x, b1.x, t1); t1 = fmaf(c[g+1].y, b1.y, t1);
    t1 = fmaf(c[g+1].z, b1.z, t1); t1 = fmaf(c[g+1].w, b1.w, t1);
    t2 = fmaf(c[g+2].x, b2.x, t2); t2 = fmaf(c[g+2].y, b2.y, t2);
    t2 = fmaf(c[g+2].z, b2.z, t2); t2 = fmaf(c[g+2].w, b2.w, t2);
    t3 = fmaf(c[g+3].x, b3.x, t3); t3 = fmaf(c[g+3].y, b3.y, t3);
    t3 = fmaf(c[g+3].z, b3.z, t3); t3 = fmaf(c[g+3].w, b3.w, t3);
  }
  o0 = (s0 + s1) + (s2 + s3);
  o1 = (t0 + t1) + (t2 + t3);
}

__device__ __forceinline__ float dot16(const float* __restrict__ row,
                                       const float* __restrict__ vec, int lane) {
  float4 a[16];
  #pragma unroll
  for (int g = 0; g < 16; ++g)
    a[g] = *reinterpret_cast<const float4*>(row + g * 256 + lane * 4);
  float s0 = 0.f, s1 = 0.f, s2 = 0.f, s3 = 0.f;
  #pragma unroll
  for (int g = 0; g < 16; g += 4) {
    float4 b0 = *reinterpret_cast<const float4*>(vec + (g + 0) * 256 + lane * 4);
    float4 b1 = *reinterpret_cast<const float4*>(vec + (g + 1) * 256 + lane * 4);
    float4 b2 = *reinterpret_cast<const float4*>(vec + (g + 2) * 256 + lane * 4);
    float4 b3 = *reinterpret_cast<const float4*>(vec + (g + 3) * 256 + lane * 4);
    s0 = fmaf(a[g+0].x, b0.x, s0); s0 = fmaf(a[g+0].y, b0.y, s0);
    s0 = fmaf(a[g+0].z, b0.z, s0); s0 = fmaf(a[g+0].w, b0.w, s0);
    s1 = fmaf(a[g+1].x, b1.x, s1); s1 = fmaf(a[g+1].y, b1.y, s1);
    s1 = fmaf(a[g+1].z, b1.z, s1); s1 = fmaf(a[g+1].w, b1.w, s1);
    s2 = fmaf(a[g+2].x, b2.x, s2); s2 = fmaf(a[g+2].y, b2.y, s2);
    s2 = fmaf(a[g+2].z, b2.z, s2); s2 = fmaf(a[g+2].w, b2.w, s2);
    s3 = fmaf(a[g+3].x, b3.x, s3); s3 = fmaf(a[g+3].y, b3.y, s3);
    s3 = fmaf(a[g+3].z, b3.z, s3); s3 = fmaf(a[g+3].w, b3.w, s3);
  }
  return (s0 + s1) + (s2 + s3);
}

__global__ void __launch_bounds__(BLOCK, 2) reasoning_kernel(Params p) {
  const int tid = blockIdx.x * blockDim.x + threadIdx.x;
  const int nth = gridDim.x * blockDim.x;
  const int lane = threadIdx.x & 63;
  const int wid = threadIdx.x >> 6;
  const int gw = tid >> 6;
  const int nw = nth >> 6;

  __shared__ __align__(16) float sh_h[H];
  __shared__ __align__(16) float sh_l[D];
  __shared__ __align__(16) float sh_dir[D];
  __shared__ float sh_red[32];

  float* qc   = p.ws;            // 3H
  float* gi_l = qc + 3 * H;      // 3H
  float* ghh  = gi_l + 3 * H;    // 3H
  float* ghl2 = ghh + 3 * H;     // 2 x 3D parity ping-pong
  float* gil  = ghl2 + 6 * D;    // 3D
  float* dirv = gil + 3 * D;     // D  (also reused as reset projection)
  unsigned* bar = (unsigned*)(p.ws + BAR_OFF_FLOATS);

  for (int j = threadIdx.x; j < H; j += blockDim.x) sh_h[j] = 0.f;
  for (int j = threadIdx.x; j < D; j += blockDim.x) sh_l[j] = 0.f;
  __syncthreads();

  float cum = 0.f, rw = 0.f, mom = 0.f;
  float rawconv = 0.f, halt_h = 0.f, reset_h = 0.f;
  float sum0 = 0.f, sum1 = 0.f;
  const bool owner = (gw < D / 2);
  unsigned mygen = 0;

  for (int step = 0; step < MAX_STEPS; ++step) {
    const int par = step & 1;
    const bool upd = (step & 3) == 0;
    float* ghl = ghl2 + par * 3 * D;

    // ---------------- A phase (grid-distributed dots) ----------------
    if (upd) {
      if (step == 0) {
        for (int t = gw * 2; t < 3 * H; t += nw * 2) {   // 6144 pairs / 2048 waves = 3 (balanced)
          float o0, o1;
          dot8x2(p.hg_Wih + (size_t)t * (2 * D),
                 p.hg_Wih + (size_t)(t + 1) * (2 * D), p.query, lane, o0, o1);
          o0 = wred(o0); o1 = wred(o1);
          if (lane == 0) { cstore(qc + t, o0); cstore(qc + t + 1, o1); }
        }
      } else {
        for (int t = gw * 2; t < 3 * H; t += nw * 2) {      // gi l-part
          float o0, o1;
          dot8x2(p.hg_Wih + (size_t)t * (2 * D) + D,
                 p.hg_Wih + (size_t)(t + 1) * (2 * D) + D, sh_l, lane, o0, o1);
          o0 = wred(o0); o1 = wred(o1);
          if (lane == 0) { cstore(gi_l + t, o0); cstore(gi_l + t + 1, o1); }
        }
        for (int t = gw; t < 3 * H; t += nw) {              // Whh @ h
          float s = wred(dot16(p.hg_Whh + (size_t)t * H, sh_h, lane));
          if (lane == 0) cstore(ghh + t, s + p.hg_bhh[t]);
        }
        for (int t = gw * 2; t < 2 * D; t += nw * 2) {      // lg_Whh rows 0..4095 (pairs)
          float o0, o1;
          dot8x2(p.lg_Whh + (size_t)t * D,
                 p.lg_Whh + (size_t)(t + 1) * D, sh_l, lane, o0, o1);
          o0 = wred(o0); o1 = wred(o1);
          if (lane == 0) { cstore(ghl + t, o0 + p.lg_bhh[t]); cstore(ghl + t + 1, o1 + p.lg_bhh[t + 1]); }
        }
        for (int t = 2 * D + gw; t < 3 * D; t += nw) {      // rows 4096..6143 (singles)
          float s = wred(dot8(p.lg_Whh + (size_t)t * D, sh_l, lane));
          if (lane == 0) cstore(ghl + t, s + p.lg_bhh[t]);
        }
      }
    } else {
      // balanced: 2048 pairs (rows 0..4095) + 2048 singles (rows 4096..6143)
      for (int t = gw * 2; t < 2 * D; t += nw * 2) {
        float o0, o1;
        dot8x2(p.lg_Whh + (size_t)t * D,
               p.lg_Whh + (size_t)(t + 1) * D, sh_l, lane, o0, o1);
        o0 = wred(o0); o1 = wred(o1);
        if (lane == 0) { cstore(ghl + t, o0 + p.lg_bhh[t]); cstore(ghl + t + 1, o1 + p.lg_bhh[t + 1]); }
      }
      for (int t = 2 * D + gw; t < 3 * D; t += nw) {
        float s = wred(dot8(p.lg_Whh + (size_t)t * D, sh_l, lane));
        if (lane == 0) cstore(ghl + t, s + p.lg_bhh[t]);
      }
    }
    gridbar(bar, mygen);  // S1

    if (upd) {
      // ---- h-combine, block-local ----
      if (step == 0) {
        for (int i = threadIdx.x; i < H; i += blockDim.x) {
          float r = sigmoidf_(cload(qc + i) + p.hg_bih[i] + p.hg_bhh[i]);
          float z = sigmoidf_(cload(qc + H + i) + p.hg_bih[H + i] + p.hg_bhh[H + i]);
          float n = tanhf(cload(qc + 2 * H + i) + p.hg_bih[2 * H + i] + r * p.hg_bhh[2 * H + i]);
          sh_h[i] = (1.f - z) * n;
        }
      } else {
        for (int i = threadIdx.x; i < H; i += blockDim.x) {
          float r = sigmoidf_(cload(qc + i) + cload(gi_l + i) + p.hg_bih[i] + cload(ghh + i));
          float z = sigmoidf_(cload(qc + H + i) + cload(gi_l + H + i) + p.hg_bih[H + i] + cload(ghh + H + i));
          float n = tanhf(cload(qc + 2 * H + i) + cload(gi_l + 2 * H + i) + p.hg_bih[2 * H + i]
                          + r * cload(ghh + 2 * H + i));
          sh_h[i] = (1.f - z) * n + z * sh_h[i];
        }
      }
      __syncthreads();

      // ---- block-local h scalars ----
      {
        float a0 = 0.f, a1 = 0.f, a2 = 0.f;
        for (int k = threadIdx.x; k < H; k += BLOCK) {
          float hv = sh_h[k];
          a0 = fmaf(p.hc_W[k], hv, a0);
          a1 = fmaf(p.halt_W[k], hv, a1);
          a2 = fmaf(p.reset_W[k], hv, a2);
        }
        a0 = wred(a0); a1 = wred(a1); a2 = wred(a2);
        if (lane == 0) { sh_red[wid] = a0; sh_red[8 + wid] = a1; sh_red[16 + wid] = a2; }
        __syncthreads();
        float t0 = 0.f, t1 = 0.f, t2 = 0.f;
        #pragma unroll
        for (int w = 0; w < 8; ++w) { t0 += sh_red[w]; t1 += sh_red[8 + w]; t2 += sh_red[16 + w]; }
        rawconv = sigmoidf_(t0 + p.hc_b[0]);
        halt_h = t1; reset_h = t2;
        __syncthreads();
      }

      // ---- dirv dots (balanced: 2048 / 2048 waves) ----
      for (int t = gw; t < D; t += nw) {
        float s = wred(dot16(p.hd_W + (size_t)t * H, sh_h, lane));
        if (lane == 0) cstore(dirv + t, tanhf(s + p.hd_b[t]));
      }
      gridbar(bar, mygen);  // S2

      for (int j = threadIdx.x; j < D; j += blockDim.x) sh_dir[j] = cload(dirv + j);
      __syncthreads();

      // ---- gil (balanced pairs + singles) ----
      for (int t = gw * 2; t < 2 * D; t += nw * 2) {
        float o0, o1;
        dot8x2(p.lg_Wih + (size_t)t * D,
               p.lg_Wih + (size_t)(t + 1) * D, sh_dir, lane, o0, o1);
        o0 = wred(o0); o1 = wred(o1);
        if (lane == 0) { cstore(gil + t, o0 + p.lg_bih[t]); cstore(gil + t + 1, o1 + p.lg_bih[t + 1]); }
      }
      for (int t = 2 * D + gw; t < 3 * D; t += nw) {
        float s = wred(dot8(p.lg_Wih + (size_t)t * D, sh_dir, lane));
        if (lane == 0) cstore(gil + t, s + p.lg_bih[t]);
      }
      gridbar(bar, mygen);  // S3
    }

    // ---- l-combine, block-local ----
    if (step == 0) {
      for (int j = threadIdx.x; j < D; j += blockDim.x) {
        float r = sigmoidf_(cload(gil + j) + p.lg_bhh[j]);
        float z = sigmoidf_(cload(gil + D + j) + p.lg_bhh[D + j]);
        float n = tanhf(cload(gil + 2 * D + j) + r * p.lg_bhh[2 * D + j]);
        sh_l[j] = (1.f - z) * n;
      }
    } else {
      for (int j = threadIdx.x; j < D; j += blockDim.x) {
        float r = sigmoidf_(cload(gil + j) + cload(ghl + j));
        float z = sigmoidf_(cload(gil + D + j) + cload(ghl + D + j));
        float n = tanhf(cload(gil + 2 * D + j) + r * cload(ghl + 2 * D + j));
        sh_l[j] = (1.f - z) * n + z * sh_l[j];
      }
    }
    __syncthreads();

    // ---- block-local l scalars ----
    float halt_l, reset_l;
    {
      float a0 = 0.f, a1 = 0.f;
      for (int k = threadIdx.x; k < D; k += BLOCK) {
        float lv = sh_l[k];
        a0 = fmaf(p.halt_W[H + k], lv, a0);
        a1 = fmaf(p.reset_W[H + k], lv, a1);
      }
      a0 = wred(a0); a1 = wred(a1);
      if (lane == 0) { sh_red[wid] = a0; sh_red[8 + wid] = a1; }
      __syncthreads();
      float t0 = 0.f, t1 = 0.f;
      #pragma unroll
      for (int w = 0; w < 8; ++w) { t0 += sh_red[w]; t1 += sh_red[8 + w]; }
      halt_l = t0; reset_l = t1;
      __syncthreads();
    }

    // ---- scalar resolution (uniform, block-local) ----
    mom = MOMC * mom + (1.f - MOMC) * rawconv;
    float halt = sigmoidf_(halt_h + halt_l + p.halt_b[0]);
    float pp = fminf(halt, 1.f - cum);
    cum += pp; rw += pp;
    bool converged = cum > 0.95f;

    // ---- res rows: owner waves accumulate into registers ----
    if (owner) {
      int t = gw * 2;
      float o0, o1;
      dot8x2(p.lo_W + (size_t)t * D, p.lo_W + (size_t)(t + 1) * D, sh_l, lane, o0, o1);
      o0 = wred(o0); o1 = wred(o1);
      sum0 += pp * tanhf(o0 + p.lo_b[t]);
      sum1 += pp * tanhf(o1 + p.lo_b[t + 1]);
    }
    if (converged) break;

    float reset_p = sigmoidf_(reset_h + reset_l + p.reset_W[H + D] * mom + p.reset_b[0]);
    if ((reset_p > 0.7f) && (step > KSTEP)) {  // uniform across blocks
      for (int t = gw; t < D; t += nw) {
        float s = wred(dot16(p.li_W + (size_t)t * H, sh_h, lane));
        if (lane == 0) cstore(dirv + t, tanhf(s + p.li_b[t]));
      }
      gridbar(bar, mygen);
      for (int j = threadIdx.x; j < D; j += blockDim.x) sh_l[j] = cload(dirv + j);
      __syncthreads();
    }
  }

  if (owner && lane == 0) {
    float inv = 1.f / fmaxf(rw, 1e-8f);
    p.out[2 * gw]     = sum0 * inv;
    p.out[2 * gw + 1] = sum1 * inv;
  }
}

extern "C" void kernel_launch(void* const* d_in, const int* in_sizes, int n_in,
                              void* d_out, int out_size, void* d_ws, size_t ws_size,
                              hipStream_t stream) {
  Params prm;
  prm.query   = (const float*)d_in[0];
  prm.hg_Wih  = (const float*)d_in[1];
  prm.hg_Whh  = (const float*)d_in[2];
  prm.hg_bih  = (const float*)d_in[3];
  prm.hg_bhh  = (const float*)d_in[4];
  prm.hd_W    = (const float*)d_in[5];
  prm.hd_b    = (const float*)d_in[6];
  prm.hc_W    = (const float*)d_in[7];
  prm.hc_b    = (const float*)d_in[8];
  prm.lg_Wih  = (const float*)d_in[9];
  prm.lg_Whh  = (const float*)d_in[10];
  prm.lg_bih  = (const float*)d_in[11];
  prm.lg_bhh  = (const float*)d_in[12];
  prm.lo_W    = (const float*)d_in[13];
  prm.lo_b    = (const float*)d_in[14];
  prm.halt_W  = (const float*)d_in[15];
  prm.halt_b  = (const float*)d_in[16];
  prm.reset_W = (const float*)d_in[17];
  prm.reset_b = (const float*)d_in[18];
  prm.li_W    = (const float*)d_in[19];
  prm.li_b    = (const float*)d_in[20];
  prm.ws  = (float*)d_ws;
  prm.out = (float*)d_out;

  // zero barrier counters (in-bounds: 229376..233471 < 254016 proven) each launch
  hipMemsetAsync((char*)d_ws + (size_t)BAR_OFF_FLOATS * sizeof(float), 0, 4096, stream);

  void* args[] = { &prm };
  const int grids[3] = { GRID, GRID / 2, GRID / 4 };  // multiples of 16
  for (int g = 0; g < 3; ++g) {
    hipError_t e = hipLaunchCooperativeKernel((const void*)reasoning_kernel,
                                              dim3(grids[g]), dim3(BLOCK),
                                              args, 0, stream);
    if (e == hipSuccess) break;
  }
}